// Round 11
// baseline (231.861 us; speedup 1.0000x reference)
//
#include <hip/hip_runtime.h>

#define N_NODES 6000
#define DEG_    16
#define N_EDGES (N_NODES*DEG_)
#define D_MODEL 256
#define D_MSG   64
#define D_FF    1024

typedef __bf16 bf16x8 __attribute__((ext_vector_type(8)));
typedef float floatx4 __attribute__((ext_vector_type(4)));

__device__ __forceinline__ float silu_f(float v) {
    return v * __builtin_amdgcn_rcpf(1.0f + __expf(-v));
}
__device__ __forceinline__ float b2f(unsigned short u) {
    union { unsigned int i; float f; } v; v.i = ((unsigned int)u) << 16; return v.f;
}
__device__ __forceinline__ unsigned short f2b(float f) {
    union { float f; unsigned int i; } v; v.f = f;
    unsigned int r = (v.i + 0x7FFFu + ((v.i >> 16) & 1u)) >> 16;
    return (unsigned short)r;
}

// ---------------- prep (fast branches only): weight cvt + embed + geom + frag packs ----------------
#define WSRC_OFF 0
#define WDST_OFF 49152
#define WCVT_TOTAL 98304
#define CVT4_BLOCKS (WCVT_TOTAL/4/256)         // 96
#define EMB4_BLOCKS (N_NODES*D_MODEL/4/256)    // 1500
#define GEOM_BLOCKS (N_EDGES/256)              // 375
#define WPACKE_BLOCKS 24                       // Wedge pack: 6144 lane-frags
#define WPACK1_BLOCKS 96                       // W1 pack (3 layers): 24576 lane-frags
__global__ __launch_bounds__(256) void prep_kernel(
    const float* __restrict__ Wsrc, const float* __restrict__ Wdst,
    const float* __restrict__ Wedge, const float* __restrict__ W1,
    unsigned short* __restrict__ wbf_out,
    const int* __restrict__ an, const float* __restrict__ emb,
    unsigned short* __restrict__ x,
    const float* __restrict__ r, float* __restrict__ d, float* __restrict__ rhat,
    unsigned short* __restrict__ wedgep,     // PACKED [6144 frags][8]
    unsigned short* __restrict__ w1p) {      // PACKED [3 layers][8192 frags][8]
    int b = blockIdx.x;
    int t = threadIdx.x;
    if (b < CVT4_BLOCKS) {
        int i = (b*256 + t) * 4;
        const float* sp = (i < WDST_OFF) ? (Wsrc + i) : (Wdst + (i - WDST_OFF));
        float4 v = *(const float4*)sp;
        *(ushort4*)(wbf_out + i) = make_ushort4(f2b(v.x), f2b(v.y), f2b(v.z), f2b(v.w));
    } else if (b < CVT4_BLOCKS + EMB4_BLOCKS) {
        int i4 = (b - CVT4_BLOCKS)*256 + t;
        int node = i4 >> 6, c4 = i4 & 63;
        float4 v = *(const float4*)(emb + (size_t)an[node]*D_MODEL + c4*4);
        *(ushort4*)(x + (size_t)node*D_MODEL + c4*4) =
            make_ushort4(f2b(v.x), f2b(v.y), f2b(v.z), f2b(v.w));
    } else if (b < CVT4_BLOCKS + EMB4_BLOCKS + GEOM_BLOCKS) {
        int e = (b - CVT4_BLOCKS - EMB4_BLOCKS)*256 + t;
        float xx = r[e*3+0], yy = r[e*3+1], zz = r[e*3+2];
        float n = sqrtf(xx*xx + yy*yy + zz*zz);
        d[e] = n;
        float inv = 1.0f / n;
        *(float4*)(rhat + (size_t)e*4) = make_float4(xx*inv, yy*inv, zz*inv, 0.f);
    } else if (b < CVT4_BLOCKS + EMB4_BLOCKS + GEOM_BLOCKS + WPACKE_BLOCKS) {
        // Wedge fragment pack: i = ((w*3+ns)*8+ks)*64 + lane, i in [0,6144)
        int wb = b - (CVT4_BLOCKS + EMB4_BLOCKS + GEOM_BLOCKS);
        int i = wb*256 + t;                  // 0..6143
        int lane = i & 63, ks = (i >> 6) & 7, rem = i >> 9;   // rem 0..11
        int ns = rem % 3, w = rem / 3;                        // w 0..3
        int row = 48*w + ns*16 + (lane & 15);
        int col = ks*32 + (lane >> 4)*8;
        const float* sp = Wedge + (size_t)row*256 + col;
        float4 v0 = *(const float4*)sp;
        float4 v1 = *(const float4*)(sp + 4);
        unsigned short h[8] = { f2b(v0.x), f2b(v0.y), f2b(v0.z), f2b(v0.w),
                                f2b(v1.x), f2b(v1.y), f2b(v1.z), f2b(v1.w) };
        *(uint4*)(wedgep + (size_t)i*8) = *(uint4*)h;
    } else {
        // W1 fragment pack (3 layers): i2 = lp*8192 + f*512 + wv*128 + j*64 + lane
        int wb = b - (CVT4_BLOCKS + EMB4_BLOCKS + GEOM_BLOCKS + WPACKE_BLOCKS);
        int i2 = wb*256 + t;                 // 0..24575
        int lp = i2 >> 13;                   // 0..2
        int e = i2 & 8191;
        int lane = e & 63, j = (e >> 6) & 1, wv = (e >> 7) & 3, f = e >> 9;
        int row = f*64 + wv*16 + (lane & 15);
        int col = j*32 + (lane >> 4)*8;
        const float* sp = W1 + (size_t)lp*65536 + (size_t)row*64 + col;
        float4 v0 = *(const float4*)sp;
        float4 v1 = *(const float4*)(sp + 4);
        unsigned short h[8] = { f2b(v0.x), f2b(v0.y), f2b(v0.z), f2b(v0.w),
                                f2b(v1.x), f2b(v1.y), f2b(v1.z), f2b(v1.w) };
        *(uint4*)(w1p + (size_t)i2*8) = *(uint4*)h;
    }
}

// ---------------- merged eproj + layer0 xj/xi GEMM + wcomb/wfc2/bcomb precompute ----------------
// eproj branch v3: LDS-FREE. Wave w owns rows [16w,16w+16) x all 192 cols. Each lane computes
// its own RBF A-fragments in registers (af[8], 64 exps) -- no LDS panel, no barriers. LDS block
// size drops 33792 -> 10240 B (GEMM branch only) => 6 blocks/CU residency (was 1; 64KB pool).
#define APITCH 40
#define MCP 72
__global__ __launch_bounds__(256) void eplg_kernel(
    const unsigned short* __restrict__ Bwp,  // PACKED Wedge frags
    const float* __restrict__ bias,          // bedge [192]
    const float* __restrict__ dvec,          // [E]
    unsigned short* __restrict__ C,          // eproj out [E,192]
    const unsigned short* __restrict__ A,    // d_x [N,256]
    const unsigned short* __restrict__ B1g,  // wsrc [64,256] bf16
    const unsigned short* __restrict__ B2g,  // wdst [64,256] bf16
    const float* __restrict__ bias1,         // bsrc
    const float* __restrict__ bias2,         // bdst
    unsigned short* __restrict__ Cg,         // d_xjxi [N,128]
    const float* __restrict__ Wsrc, const float* __restrict__ Wdst,
    const float* __restrict__ W2, const float* __restrict__ b2,
    const float* __restrict__ Wfc, const float* __restrict__ bfc,
    unsigned short* __restrict__ wcomb,      // PACKED [2 layers][16384 frags][8]
    float* __restrict__ bcomb,
    float* __restrict__ wfc2,
    float* __restrict__ out) {
    __shared__ __align__(16) unsigned short sm[5120];   // 10240 B (GEMM branch only)
    const int t = threadIdx.x;
    const int w = t >> 6, lane = t & 63, lr = lane & 15, lq = lane >> 4;

    if (blockIdx.x < 1500) {
        // ================= eproj (LDS-free, barrier-free) =================
        const int m0 = blockIdx.x * 64;
        float dv = dvec[m0 + w*16 + lr];
        const float gamma = 31.875f;
        const float step  = 8.0f / 255.0f;
        // A fragments in registers: af[ks] holds row (m0+16w+lr), k = ks*32 + lq*8 .. +7
        bf16x8 af[8];
        #pragma unroll
        for (int ks = 0; ks < 8; ++ks) {
            unsigned short h[8];
            int kb = ks*32 + lq*8;
            #pragma unroll
            for (int j = 0; j < 8; ++j) {
                float tt2 = dv - (float)(kb+j)*step;
                h[j] = f2b(__expf(-gamma*tt2*tt2));
            }
            af[ks] = *(bf16x8*)h;
        }
        const unsigned short* Bl = Bwp + lane*8;
        #pragma unroll
        for (int ct = 0; ct < 12; ++ct) {
            const unsigned short* Bb = Bl + (ct/3)*12288 + (ct%3)*4096;
            uint4 pb[8];
            #pragma unroll
            for (int ks = 0; ks < 8; ++ks)
                pb[ks] = *(const uint4*)(Bb + ks*512);
            floatx4 acc = {};
            #pragma unroll
            for (int ks = 0; ks < 8; ++ks)
                acc = __builtin_amdgcn_mfma_f32_16x16x32_bf16(
                    af[ks], *(const bf16x8*)&pb[ks], acc, 0, 0, 0);
            int bc = (ct/3)*48 + (ct%3)*16 + lr;
            float bv = bias[bc];
            #pragma unroll
            for (int rg = 0; rg < 4; ++rg) {
                int row = m0 + w*16 + lq*4 + rg;
                C[(size_t)row*192 + bc] = f2b(acc[rg] + bv);
            }
        }
        return;
    }
    if (blockIdx.x < 1688) {
        // ================= layer0 dual-B GEMM (K=256, M=6000) =================
        unsigned short* As = sm;          // 2560 ushorts
        unsigned short* Bs = sm + 2560;   // 2560 ushorts
        unsigned short* Cs = sm;          // 64*72 epilogue reuse (4608)
        const int bid2 = blockIdx.x - 1500;
        const int bx = bid2 & 1;
        const int m0 = (bid2 >> 1) * 64;
        const unsigned short* B = bx ? B2g : B1g;
        const float* biasl = bx ? bias2 : bias1;
        const int n0 = bx * 64;
        const int K = 256, M = N_NODES, lda = 256, ldb = 256, ldc = 128;

        const int arow = t >> 2, achk = t & 3;

        floatx4 acc[4] = {};
        uint4 pa, pb;
        {
            int gm = m0 + arow;
            pa = (gm < M) ? *(const uint4*)(A + (size_t)gm*lda + achk*8) : make_uint4(0,0,0,0);
        }
        pb = *(const uint4*)(B + (size_t)arow*ldb + achk*8);

        for (int k0 = 0; k0 < K; k0 += 32) {
            *(uint4*)(&As[arow*APITCH + achk*8]) = pa;
            *(uint4*)(&Bs[arow*APITCH + achk*8]) = pb;
            __syncthreads();
            if (k0 + 32 < K) {
                int kn = k0 + 32;
                int gm = m0 + arow;
                pa = (gm < M) ? *(const uint4*)(A + (size_t)gm*lda + kn + achk*8) : make_uint4(0,0,0,0);
                pb = *(const uint4*)(B + (size_t)arow*ldb + kn + achk*8);
            }
            bf16x8 af, bfr[4];
            af = *(const bf16x8*)(&As[(w*16 + lr)*APITCH + lq*8]);
            #pragma unroll
            for (int ns = 0; ns < 4; ++ns)
                bfr[ns] = *(const bf16x8*)(&Bs[(ns*16 + lr)*APITCH + lq*8]);
            #pragma unroll
            for (int ns = 0; ns < 4; ++ns)
                acc[ns] = __builtin_amdgcn_mfma_f32_16x16x32_bf16(af, bfr[ns], acc[ns], 0,0,0);
            __syncthreads();
        }
        #pragma unroll
        for (int ns = 0; ns < 4; ++ns) {
            int bc = ns*16 + lr;
            float bv = biasl[bc];
            #pragma unroll
            for (int rg = 0; rg < 4; ++rg) {
                int lrow = w*16 + lq*4 + rg;
                Cs[lrow*MCP + bc] = f2b(acc[ns][rg] + bv);
            }
        }
        __syncthreads();
        #pragma unroll
        for (int it = 0; it < 2; ++it) {
            int i = t + it*256;
            int row = i >> 3, c8 = i & 7;
            int gm = m0 + row;
            if (gm < M)
                *(uint4*)(Cg + (size_t)gm*ldc + n0 + c8*8) = *(const uint4*)(Cs + row*MCP + c8*8);
        }
        return;
    }
    // ================= wcomb/wfc2/bcomb branch =================
    {
        int b = blockIdx.x - 1688;       // 0..68
        if (b < 64) {
            int lp  = 1 + (b >> 5);      // layer index 1,2
            int wb2 = b & 31;            // 32 blocks/layer
            const float* W2f = W2 + (size_t)(lp-1)*262144;
            const float* wm[4];
            #pragma unroll
            for (int i = 0; i < 4; ++i) {
                int row = wb2*4 + i;
                wm[i] = (row < 64) ? (Wsrc + (size_t)lp*16384 + row*256)
                                   : (Wdst + (size_t)lp*16384 + (row-64)*256);
            }
            float acc[4][4] = {};
            int c0 = t*4;
            #pragma unroll 8
            for (int c = 0; c < 256; ++c) {
                float4 w2v = *(const float4*)(W2f + (size_t)c*1024 + c0);
                #pragma unroll
                for (int i = 0; i < 4; ++i) {
                    float wv2 = wm[i][c];
                    acc[i][0] = fmaf(wv2, w2v.x, acc[i][0]);
                    acc[i][1] = fmaf(wv2, w2v.y, acc[i][1]);
                    acc[i][2] = fmaf(wv2, w2v.z, acc[i][2]);
                    acc[i][3] = fmaf(wv2, w2v.w, acc[i][3]);
                }
            }
            int fc = t >> 4, j = (t >> 3) & 1, lq2 = (t >> 1) & 3, cpos = (t & 1) * 4;
            #pragma unroll
            for (int i = 0; i < 4; ++i) {
                int row = wb2*4 + i;
                int wv2 = row >> 5, ns = (row >> 4) & 1, lr2 = row & 15;
                *(ushort4*)(wcomb + (size_t)(lp-1)*131072
                            + (size_t)fc*8192 + wv2*2048 + ns*1024 + j*512 + (lq2*16+lr2)*8 + cpos) =
                    make_ushort4(f2b(acc[i][0]), f2b(acc[i][1]), f2b(acc[i][2]), f2b(acc[i][3]));
            }
        } else if (b < 68) {
            int c = (b - 64)*256 + t;
            const float* W2f = W2 + 2*262144;
            float a0 = 0.f, a1 = 0.f, a2 = 0.f, a3 = 0.f;
            #pragma unroll 4
            for (int k = 0; k < 256; k += 4) {
                a0 = fmaf(Wfc[k+0], W2f[(size_t)(k+0)*1024 + c], a0);
                a1 = fmaf(Wfc[k+1], W2f[(size_t)(k+1)*1024 + c], a1);
                a2 = fmaf(Wfc[k+2], W2f[(size_t)(k+2)*1024 + c], a2);
                a3 = fmaf(Wfc[k+3], W2f[(size_t)(k+3)*1024 + c], a3);
            }
            wfc2[c] = (a0 + a1) + (a2 + a3);
        } else {
            int lp = 1 + (t >> 7);
            int row = t & 127;
            const float* b2l = b2 + (lp-1)*256;
            const float* wmrow = (row < 64) ? (Wsrc + (size_t)lp*16384 + row*256)
                                            : (Wdst + (size_t)lp*16384 + (row-64)*256);
            float acc = 0.f;
            #pragma unroll 8
            for (int c = 0; c < 256; ++c) acc += wmrow[c] * b2l[c];
            acc += (row < 64) ? bias1[lp*64 + row] : bias2[lp*64 + (row-64)];
            bcomb[(lp-1)*128 + row] = acc;
            if (t == 0) {
                float bo = 0.f;
                const float* b23 = b2 + 2*256;
                #pragma unroll 8
                for (int c = 0; c < 256; ++c) bo += Wfc[c] * b23[c];
                out[0] = bo + bfc[0];
            }
        }
    }
}

// ---------------- fused FF + wcomb with PACKED weight fragments ----------------
#define HP 72
#define CP2 136
__global__ __launch_bounds__(256) void ffw_kernel(
    const unsigned short* __restrict__ XN,   // [N,64] bf16
    const unsigned short* __restrict__ W1p,  // PACKED W1 frags (this layer)
    const float* __restrict__ b1l,           // [1024]
    const unsigned short* __restrict__ WCp,  // PACKED wcomb frags (this layer)
    const float* __restrict__ bcl,           // [128]
    unsigned short* __restrict__ XO,         // [N,128] bf16
    int M) {
    __shared__ __align__(16) unsigned short s_h[16*HP];    // h chunk [16][72]
    __shared__ __align__(16) unsigned short s_c[16*CP2];   // epilogue [16][136]
    const int t = threadIdx.x;
    const int wv = t >> 6, lane = t & 63, lr = lane & 15, lq = lane >> 4;
    const int m0 = blockIdx.x * 16;

    int ga = m0 + lr;
    bool aok = ga < M;
    uint4 a0 = aok ? *(const uint4*)(XN + (size_t)ga*64 + lq*8) : make_uint4(0,0,0,0);
    uint4 a1 = aok ? *(const uint4*)(XN + (size_t)ga*64 + 32 + lq*8) : make_uint4(0,0,0,0);

    floatx4 acc2[2] = {};

    const unsigned short* W1b = W1p + (size_t)wv*1024 + lane*8;   // + f*4096 + j*512
    const unsigned short* WCb = WCp + (size_t)wv*2048 + lane*8;   // + f*8192 + ns*1024 + j*512

    uint4 pb1[2], pb2[4];
    pb1[0] = *(const uint4*)(W1b);
    pb1[1] = *(const uint4*)(W1b + 512);
    pb2[0] = *(const uint4*)(WCb);
    pb2[1] = *(const uint4*)(WCb + 512);
    pb2[2] = *(const uint4*)(WCb + 1024);
    pb2[3] = *(const uint4*)(WCb + 1536);

    for (int f = 0; f < 16; ++f) {
        uint4 cb1_0 = pb1[0], cb1_1 = pb1[1];
        uint4 cb2_0 = pb2[0], cb2_1 = pb2[1], cb2_2 = pb2[2], cb2_3 = pb2[3];
        float bv1 = b1l[f*64 + wv*16 + lr];
        if (f < 15) {
            const unsigned short* n1 = W1b + (f+1)*4096;
            const unsigned short* n2 = WCb + (f+1)*8192;
            pb1[0] = *(const uint4*)(n1);
            pb1[1] = *(const uint4*)(n1 + 512);
            pb2[0] = *(const uint4*)(n2);
            pb2[1] = *(const uint4*)(n2 + 512);
            pb2[2] = *(const uint4*)(n2 + 1024);
            pb2[3] = *(const uint4*)(n2 + 1536);
        }
        floatx4 hacc = {};
        hacc = __builtin_amdgcn_mfma_f32_16x16x32_bf16(
            *(const bf16x8*)&a0, *(const bf16x8*)&cb1_0, hacc, 0,0,0);
        hacc = __builtin_amdgcn_mfma_f32_16x16x32_bf16(
            *(const bf16x8*)&a1, *(const bf16x8*)&cb1_1, hacc, 0,0,0);
        {
            int col = wv*16 + lr;
            #pragma unroll
            for (int rg = 0; rg < 4; ++rg) {
                int row = lq*4 + rg;
                s_h[row*HP + col] = f2b(silu_f(hacc[rg] + bv1));
            }
        }
        __syncthreads();
        bf16x8 ha0 = *(const bf16x8*)(&s_h[lr*HP + lq*8]);
        bf16x8 ha1 = *(const bf16x8*)(&s_h[lr*HP + 32 + lq*8]);
        acc2[0] = __builtin_amdgcn_mfma_f32_16x16x32_bf16(ha0, *(const bf16x8*)&cb2_0, acc2[0], 0,0,0);
        acc2[0] = __builtin_amdgcn_mfma_f32_16x16x32_bf16(ha1, *(const bf16x8*)&cb2_1, acc2[0], 0,0,0);
        acc2[1] = __builtin_amdgcn_mfma_f32_16x16x32_bf16(ha0, *(const bf16x8*)&cb2_2, acc2[1], 0,0,0);
        acc2[1] = __builtin_amdgcn_mfma_f32_16x16x32_bf16(ha1, *(const bf16x8*)&cb2_3, acc2[1], 0,0,0);
        __syncthreads();
    }

    #pragma unroll
    for (int ns = 0; ns < 2; ++ns) {
        int col = wv*32 + ns*16 + lr;
        float bv = bcl[col];
        #pragma unroll
        for (int rg = 0; rg < 4; ++rg) {
            int row = lq*4 + rg;
            s_c[row*CP2 + col] = f2b(acc2[ns][rg] + bv);
        }
    }
    __syncthreads();
    {
        int row = t >> 4, c8 = t & 15;
        int gm = m0 + row;
        if (gm < M)
            *(uint4*)(XO + (size_t)gm*128 + c8*8) = *(const uint4*)(s_c + row*CP2 + c8*8);
    }
}

// ---------------- layer-2 FF + fused final reduction (packed W1, barrier-free loop) ----------------
__global__ __launch_bounds__(256) void ffa_kernel(
    const unsigned short* __restrict__ XN,   // [N,64] bf16
    const unsigned short* __restrict__ W1p,  // PACKED W1 frags (layer 2)
    const float* __restrict__ b1l,           // [1024]
    const float* __restrict__ wfc2,          // [1024]
    float* __restrict__ out, int M) {
    __shared__ float red[256];
    const int t = threadIdx.x;
    const int wv = t >> 6, lane = t & 63, lr = lane & 15, lq = lane >> 4;
    const int m0 = blockIdx.x * 16;

    int ga = m0 + lr;
    bool aok = ga < M;
    uint4 a0 = aok ? *(const uint4*)(XN + (size_t)ga*64 + lq*8) : make_uint4(0,0,0,0);
    uint4 a1 = aok ? *(const uint4*)(XN + (size_t)ga*64 + 32 + lq*8) : make_uint4(0,0,0,0);

    const unsigned short* W1b = W1p + (size_t)wv*1024 + lane*8;
    uint4 pb0 = *(const uint4*)(W1b);
    uint4 pb1 = *(const uint4*)(W1b + 512);

    float partial = 0.f;
    for (int f = 0; f < 16; ++f) {
        uint4 c0 = pb0, c1 = pb1;
        if (f < 15) {
            pb0 = *(const uint4*)(W1b + (f+1)*4096);
            pb1 = *(const uint4*)(W1b + (f+1)*4096 + 512);
        }
        floatx4 hacc = {};
        hacc = __builtin_amdgcn_mfma_f32_16x16x32_bf16(
            *(const bf16x8*)&a0, *(const bf16x8*)&c0, hacc, 0,0,0);
        hacc = __builtin_amdgcn_mfma_f32_16x16x32_bf16(
            *(const bf16x8*)&a1, *(const bf16x8*)&c1, hacc, 0,0,0);
        float bv1 = b1l[f*64 + wv*16 + lr];
        float wvv = wfc2[f*64 + wv*16 + lr];
        #pragma unroll
        for (int rg = 0; rg < 4; ++rg) {
            int gm = m0 + lq*4 + rg;
            if (gm < M) partial += silu_f(hacc[rg] + bv1) * wvv;
        }
    }
    red[t] = partial;
    __syncthreads();
    for (int off = 128; off > 0; off >>= 1) {
        if (t < off) red[t] += red[t+off];
        __syncthreads();
    }
    if (t == 0) atomicAdd(out, red[0] * (1.0f/(float)N_NODES));
}

// ---------------- angle attention v3: split-k logits + full-width shuffle softmax ----------------
__global__ __launch_bounds__(256) void angle_kernel(
    const unsigned short* __restrict__ xjxi,
    const unsigned short* __restrict__ eproj,
    const float* __restrict__ rhat,
    const int*   __restrict__ src,
    const float* __restrict__ attn,
    unsigned short* __restrict__ xn) {
    __shared__ __align__(16) float s_xij[16][68];
    __shared__ float s_rhat[16][4];
    __shared__ float s_logit[16][17];
    __shared__ float s_a[16][17];
    __shared__ float s_w[16];
    const int tt = threadIdx.x;
    const int node = blockIdx.x;

    if (tt < 16) {
        float4 rv = *(const float4*)(rhat + (size_t)(node*DEG_ + tt)*4);
        s_rhat[tt][0] = rv.x; s_rhat[tt][1] = rv.y; s_rhat[tt][2] = rv.z; s_rhat[tt][3] = 0.f;
        s_logit[tt][tt] = -1e30f;      // diag -> exp() == 0
    }
    {
        int p = tt >> 4, c4 = tt & 15;    // 256 threads: 16 edges x 16 chunks of 4 elems
        int e = node*DEG_ + p;
        int se = src[e];
        ushort4 aj = *(const ushort4*)(xjxi + (size_t)se*128 + c4*4);
        ushort4 ai = *(const ushort4*)(xjxi + (size_t)node*128 + 64 + c4*4);
        ushort4 ae = *(const ushort4*)(eproj + (size_t)e*192 + c4*4);
        s_xij[p][c4*4+0] = b2f(aj.x) + b2f(ai.x) + b2f(ae.x);
        s_xij[p][c4*4+1] = b2f(aj.y) + b2f(ai.y) + b2f(ae.y);
        s_xij[p][c4*4+2] = b2f(aj.z) + b2f(ai.z) + b2f(ae.z);
        s_xij[p][c4*4+3] = b2f(aj.w) + b2f(ai.w) + b2f(ae.w);
    }
    __syncthreads();
    int pp = 0, qq = 0;
    float lg = 0.f;
    if (tt < 240) {
        int pair = tt >> 1, half = tt & 1;
        pp = (int)((1.0f + sqrtf(8.0f*(float)pair + 1.0f)) * 0.5f);
        qq = pair - ((pp*(pp-1)) >> 1);
        float c = s_rhat[pp][0]*s_rhat[qq][0] + s_rhat[pp][1]*s_rhat[qq][1]
                + s_rhat[pp][2]*s_rhat[qq][2];
        c = fminf(fmaxf(c, -0.999999f), 0.999999f);
        float c2 = 2.0f * c;
        float tk0, tk1;
        if (half) {
            float T2  = fmaf(c2, c, -1.0f);
            float T3  = fmaf(2.0f*T2,  c,   -c);
            float T4  = fmaf(2.0f*T2,  T2,  -1.0f);
            float T7  = fmaf(2.0f*T4,  T3,  -c);
            float T8  = fmaf(2.0f*T4,  T4,  -1.0f);
            float T15 = fmaf(2.0f*T8,  T7,  -c);
            float T16 = fmaf(2.0f*T8,  T8,  -1.0f);
            float T31 = fmaf(2.0f*T16, T15, -c);
            float T32 = fmaf(2.0f*T16, T16, -1.0f);
            float T33 = fmaf(2.0f*T32, c,   -T31);
            tk0 = T32; tk1 = T33;
        } else {
            tk0 = 1.0f; tk1 = c;
        }
        const float* xp = &s_xij[pp][0] + half*32;
        const float* xq = &s_xij[qq][0] + half*32;
        const float* at = attn + half*32;
        float acc = 0.f;
        #pragma unroll
        for (int k0 = 0; k0 < 32; k0 += 4) {
            float4 xp4 = *(const float4*)(xp + k0);
            float4 xq4 = *(const float4*)(xq + k0);
            float a0 = at[k0+0], a1 = at[k0+1], a2 = at[k0+2], a3 = at[k0+3];
            float v0 = tk0 + xp4.x + xq4.x;
            acc = fmaf(a0, silu_f(v0), acc);
            { float tn2 = c2*tk1 - tk0; tk0 = tk1; tk1 = tn2; }
            float v1 = tk0 + xp4.y + xq4.y;
            acc = fmaf(a1, silu_f(v1), acc);
            { float tn2 = c2*tk1 - tk0; tk0 = tk1; tk1 = tn2; }
            float v2 = tk0 + xp4.z + xq4.z;
            acc = fmaf(a2, silu_f(v2), acc);
            { float tn2 = c2*tk1 - tk0; tk0 = tk1; tk1 = tn2; }
            float v3 = tk0 + xp4.w + xq4.w;
            acc = fmaf(a3, silu_f(v3), acc);
            { float tn2 = c2*tk1 - tk0; tk0 = tk1; tk1 = tn2; }
        }
        lg = acc;
    }
    lg += __shfl_xor(lg, 1);
    if (tt < 240 && (tt & 1) == 0) {
        s_logit[pp][qq] = lg;
        s_logit[qq][pp] = lg;
    }
    __syncthreads();
    // column softmax: thread (q = tt>>4, p = tt&15); shfl groups of 16 share q
    {
        int q = tt >> 4, p = tt & 15;
        float l = s_logit[p][q];
        float m = l;
        m = fmaxf(m, __shfl_xor(m, 1));
        m = fmaxf(m, __shfl_xor(m, 2));
        m = fmaxf(m, __shfl_xor(m, 4));
        m = fmaxf(m, __shfl_xor(m, 8));
        float e = __expf(l - m);
        float z = e;
        z += __shfl_xor(z, 1);
        z += __shfl_xor(z, 2);
        z += __shfl_xor(z, 4);
        z += __shfl_xor(z, 8);
        s_a[p][q] = e * __builtin_amdgcn_rcpf(z);   // attention weight, zi folded in
    }
    __syncthreads();
    // row-sum: thread (p = tt>>4, q = tt&15); sw[p] = sum_q a[p][q]
    {
        int p = tt >> 4, q = tt & 15;
        float a = s_a[p][q];
        a += __shfl_xor(a, 1);
        a += __shfl_xor(a, 2);
        a += __shfl_xor(a, 4);
        a += __shfl_xor(a, 8);
        if (q == 0) s_w[p] = a;
    }
    __syncthreads();
    if (tt < 64) {
        float acc = 0.f;
        #pragma unroll
        for (int p = 0; p < 16; ++p) acc += s_w[p] * s_xij[p][tt];
        xn[(size_t)node*64 + tt] = f2b(acc);
    }
}

extern "C" void kernel_launch(void* const* d_in, const int* in_sizes, int n_in,
                              void* d_out, int out_size, void* d_ws, size_t ws_size,
                              hipStream_t stream) {
    (void)in_sizes; (void)n_in; (void)out_size; (void)ws_size;
    const float* r    = (const float*)d_in[0];
    const int*   an   = (const int*)  d_in[1];
    const int*   src  = (const int*)  d_in[2];
    const float* emb  = (const float*)d_in[6];
    const float* Wsrc = (const float*)d_in[7];
    const float* bsrc = (const float*)d_in[8];
    const float* Wdst = (const float*)d_in[9];
    const float* bdst = (const float*)d_in[10];
    const float* Wedge= (const float*)d_in[11];
    const float* bedge= (const float*)d_in[12];
    const float* attn = (const float*)d_in[13];
    const float* W1   = (const float*)d_in[14];
    const float* b1   = (const float*)d_in[15];
    const float* W2   = (const float*)d_in[16];
    const float* b2   = (const float*)d_in[17];
    const float* Wfc  = (const float*)d_in[18];
    const float* bfc  = (const float*)d_in[19];

    char* ws = (char*)d_ws;
    float* d_d              = (float*)(ws);                    // 384000 B
    float* d_rhat           = (float*)(ws + 384000);           // 1536000 B
    unsigned short* wbf     = (unsigned short*)(ws + 1920000); // 196608 B (wsrc/wdst bf16)
    unsigned short* d_x     = (unsigned short*)(ws + 4180992); // 3072000 B
    unsigned short* d_xjxi  = (unsigned short*)(ws + 7252992); // 1536000 B
    unsigned short* d_eproj = (unsigned short*)(ws + 8788992); // 36864000 B
    unsigned short* d_xn    = (unsigned short*)(ws + 45652992);// 768000 B
    unsigned short* d_wcomb = (unsigned short*)(ws + 46420992);// 524288 B (packed)
    float* d_bcomb          = (float*)(ws + 46945280);         // 1024 B
    float* d_wfc2           = (float*)(ws + 46946304);         // 4096 B
    unsigned short* d_wedgep= (unsigned short*)(ws + 46950400);// 98304 B (packed)
    unsigned short* d_w1p   = (unsigned short*)(ws + 47048704);// 393216 B (packed, 3 layers)
    float* out = (float*)d_out;

    unsigned short* wsrc_bf  = wbf + WSRC_OFF;
    unsigned short* wdst_bf  = wbf + WDST_OFF;

    // fast prep (only what eplg needs) -> eplg starts ASAP
    prep_kernel<<<CVT4_BLOCKS + EMB4_BLOCKS + GEOM_BLOCKS + WPACKE_BLOCKS + WPACK1_BLOCKS,
                  256, 0, stream>>>(
        Wsrc, Wdst, Wedge, W1, wbf, an, emb, d_x, r, d_d, d_rhat, d_wedgep, d_w1p);

    // merged eproj + layer0 GEMM + wcomb precompute (wcomb blocks fill eproj's tail)
    eplg_kernel<<<1500 + 188 + 69, 256, 0, stream>>>(
        d_wedgep, bedge, d_d, d_eproj,
        d_x, wsrc_bf, wdst_bf, bsrc, bdst, d_xjxi,
        Wsrc, Wdst, W2, b2, Wfc, bfc,
        d_wcomb, d_bcomb, d_wfc2, out);

    // ---- layer 0 ----
    angle_kernel<<<N_NODES, 256, 0, stream>>>(
        d_xjxi, d_eproj, d_rhat, src, attn, d_xn);
    ffw_kernel<<<375, 256, 0, stream>>>(
        d_xn, d_w1p, b1, d_wcomb, d_bcomb, d_xjxi, N_NODES);

    // ---- layer 1 ----
    angle_kernel<<<N_NODES, 256, 0, stream>>>(
        d_xjxi, d_eproj + 64, d_rhat, src, attn + 64, d_xn);
    ffw_kernel<<<375, 256, 0, stream>>>(
        d_xn, d_w1p + 65536, b1 + 1024, d_wcomb + 131072, d_bcomb + 128, d_xjxi, N_NODES);

    // ---- layer 2 (FF + final reduction, packed W1, barrier-free loop) ----
    angle_kernel<<<N_NODES, 256, 0, stream>>>(
        d_xjxi, d_eproj + 128, d_rhat, src, attn + 128, d_xn);
    ffa_kernel<<<375, 256, 0, stream>>>(
        d_xn, d_w1p + 131072, b1 + 2048, d_wfc2, out, N_NODES);
}

// Round 12
// 230.068 us; speedup vs baseline: 1.0078x; 1.0078x over previous
//
#include <hip/hip_runtime.h>

#define N_NODES 6000
#define DEG_    16
#define N_EDGES (N_NODES*DEG_)
#define D_MODEL 256
#define D_MSG   64
#define D_FF    1024

typedef __bf16 bf16x8 __attribute__((ext_vector_type(8)));
typedef float floatx4 __attribute__((ext_vector_type(4)));

__device__ __forceinline__ float silu_f(float v) {
    return v * __builtin_amdgcn_rcpf(1.0f + __expf(-v));
}
__device__ __forceinline__ float b2f(unsigned short u) {
    union { unsigned int i; float f; } v; v.i = ((unsigned int)u) << 16; return v.f;
}
__device__ __forceinline__ unsigned short f2b(float f) {
    union { float f; unsigned int i; } v; v.f = f;
    unsigned int r = (v.i + 0x7FFFu + ((v.i >> 16) & 1u)) >> 16;
    return (unsigned short)r;
}

// ---------------- prep (fast branches only): weight cvt + embed + geom + frag packs ----------------
#define WSRC_OFF 0
#define WDST_OFF 49152
#define WCVT_TOTAL 98304
#define CVT4_BLOCKS (WCVT_TOTAL/4/256)         // 96
#define EMB4_BLOCKS (N_NODES*D_MODEL/4/256)    // 1500
#define GEOM_BLOCKS (N_EDGES/256)              // 375
#define WPACKE_BLOCKS 24                       // Wedge pack: 6144 lane-frags
#define WPACK1_BLOCKS 96                       // W1 pack (3 layers): 24576 lane-frags
__global__ __launch_bounds__(256) void prep_kernel(
    const float* __restrict__ Wsrc, const float* __restrict__ Wdst,
    const float* __restrict__ Wedge, const float* __restrict__ W1,
    unsigned short* __restrict__ wbf_out,
    const int* __restrict__ an, const float* __restrict__ emb,
    unsigned short* __restrict__ x,
    const float* __restrict__ r, float* __restrict__ d, float* __restrict__ rhat,
    unsigned short* __restrict__ wedgep,     // PACKED [6144 frags][8]
    unsigned short* __restrict__ w1p) {      // PACKED [3 layers][8192 frags][8]
    int b = blockIdx.x;
    int t = threadIdx.x;
    if (b < CVT4_BLOCKS) {
        int i = (b*256 + t) * 4;
        const float* sp = (i < WDST_OFF) ? (Wsrc + i) : (Wdst + (i - WDST_OFF));
        float4 v = *(const float4*)sp;
        *(ushort4*)(wbf_out + i) = make_ushort4(f2b(v.x), f2b(v.y), f2b(v.z), f2b(v.w));
    } else if (b < CVT4_BLOCKS + EMB4_BLOCKS) {
        int i4 = (b - CVT4_BLOCKS)*256 + t;
        int node = i4 >> 6, c4 = i4 & 63;
        float4 v = *(const float4*)(emb + (size_t)an[node]*D_MODEL + c4*4);
        *(ushort4*)(x + (size_t)node*D_MODEL + c4*4) =
            make_ushort4(f2b(v.x), f2b(v.y), f2b(v.z), f2b(v.w));
    } else if (b < CVT4_BLOCKS + EMB4_BLOCKS + GEOM_BLOCKS) {
        int e = (b - CVT4_BLOCKS - EMB4_BLOCKS)*256 + t;
        float xx = r[e*3+0], yy = r[e*3+1], zz = r[e*3+2];
        float n = sqrtf(xx*xx + yy*yy + zz*zz);
        d[e] = n;
        float inv = 1.0f / n;
        *(float4*)(rhat + (size_t)e*4) = make_float4(xx*inv, yy*inv, zz*inv, 0.f);
    } else if (b < CVT4_BLOCKS + EMB4_BLOCKS + GEOM_BLOCKS + WPACKE_BLOCKS) {
        // Wedge fragment pack: i = ((w*3+ns)*8+ks)*64 + lane, i in [0,6144)
        int wb = b - (CVT4_BLOCKS + EMB4_BLOCKS + GEOM_BLOCKS);
        int i = wb*256 + t;                  // 0..6143
        int lane = i & 63, ks = (i >> 6) & 7, rem = i >> 9;   // rem 0..11
        int ns = rem % 3, w = rem / 3;                        // w 0..3
        int row = 48*w + ns*16 + (lane & 15);
        int col = ks*32 + (lane >> 4)*8;
        const float* sp = Wedge + (size_t)row*256 + col;
        float4 v0 = *(const float4*)sp;
        float4 v1 = *(const float4*)(sp + 4);
        unsigned short h[8] = { f2b(v0.x), f2b(v0.y), f2b(v0.z), f2b(v0.w),
                                f2b(v1.x), f2b(v1.y), f2b(v1.z), f2b(v1.w) };
        *(uint4*)(wedgep + (size_t)i*8) = *(uint4*)h;
    } else {
        // W1 fragment pack (3 layers): i2 = lp*8192 + f*512 + wv*128 + j*64 + lane
        int wb = b - (CVT4_BLOCKS + EMB4_BLOCKS + GEOM_BLOCKS + WPACKE_BLOCKS);
        int i2 = wb*256 + t;                 // 0..24575
        int lp = i2 >> 13;                   // 0..2
        int e = i2 & 8191;
        int lane = e & 63, j = (e >> 6) & 1, wv = (e >> 7) & 3, f = e >> 9;
        int row = f*64 + wv*16 + (lane & 15);
        int col = j*32 + (lane >> 4)*8;
        const float* sp = W1 + (size_t)lp*65536 + (size_t)row*64 + col;
        float4 v0 = *(const float4*)sp;
        float4 v1 = *(const float4*)(sp + 4);
        unsigned short h[8] = { f2b(v0.x), f2b(v0.y), f2b(v0.z), f2b(v0.w),
                                f2b(v1.x), f2b(v1.y), f2b(v1.z), f2b(v1.w) };
        *(uint4*)(w1p + (size_t)i2*8) = *(uint4*)h;
    }
}

// ---------------- merged kernel, REORDERED: GEMM [0,188) + wcomb [188,257) + eproj [257,1007) ----
// The few slow GEMM/wcomb blocks now start at t=0 and overlap the 750 eproj blocks instead of
// forming a low-occupancy tail. eproj v4: LDS-free, 128 rows/block (2 row-sets/wave) -> B L2
// refetch halved vs v3; barrier-free.
#define APITCH 40
#define MCP 72
__global__ __launch_bounds__(256) void eplg_kernel(
    const unsigned short* __restrict__ Bwp,  // PACKED Wedge frags
    const float* __restrict__ bias,          // bedge [192]
    const float* __restrict__ dvec,          // [E]
    unsigned short* __restrict__ C,          // eproj out [E,192]
    const unsigned short* __restrict__ A,    // d_x [N,256]
    const unsigned short* __restrict__ B1g,  // wsrc [64,256] bf16
    const unsigned short* __restrict__ B2g,  // wdst [64,256] bf16
    const float* __restrict__ bias1,         // bsrc
    const float* __restrict__ bias2,         // bdst
    unsigned short* __restrict__ Cg,         // d_xjxi [N,128]
    const float* __restrict__ Wsrc, const float* __restrict__ Wdst,
    const float* __restrict__ W2, const float* __restrict__ b2,
    const float* __restrict__ Wfc, const float* __restrict__ bfc,
    unsigned short* __restrict__ wcomb,      // PACKED [2 layers][16384 frags][8]
    float* __restrict__ bcomb,
    float* __restrict__ wfc2,
    float* __restrict__ out) {
    __shared__ __align__(16) unsigned short sm[5120];   // 10240 B (GEMM branch only)
    const int t = threadIdx.x;
    const int w = t >> 6, lane = t & 63, lr = lane & 15, lq = lane >> 4;

    if (blockIdx.x < 188) {
        // ================= layer0 dual-B GEMM (K=256, M=6000) =================
        unsigned short* As = sm;          // 2560 ushorts
        unsigned short* Bs = sm + 2560;   // 2560 ushorts
        unsigned short* Cs = sm;          // 64*72 epilogue reuse (4608)
        const int bid2 = blockIdx.x;
        const int bx = bid2 & 1;
        const int m0 = (bid2 >> 1) * 64;
        const unsigned short* B = bx ? B2g : B1g;
        const float* biasl = bx ? bias2 : bias1;
        const int n0 = bx * 64;
        const int K = 256, M = N_NODES, lda = 256, ldb = 256, ldc = 128;

        const int arow = t >> 2, achk = t & 3;

        floatx4 acc[4] = {};
        uint4 pa, pb;
        {
            int gm = m0 + arow;
            pa = (gm < M) ? *(const uint4*)(A + (size_t)gm*lda + achk*8) : make_uint4(0,0,0,0);
        }
        pb = *(const uint4*)(B + (size_t)arow*ldb + achk*8);

        for (int k0 = 0; k0 < K; k0 += 32) {
            *(uint4*)(&As[arow*APITCH + achk*8]) = pa;
            *(uint4*)(&Bs[arow*APITCH + achk*8]) = pb;
            __syncthreads();
            if (k0 + 32 < K) {
                int kn = k0 + 32;
                int gm = m0 + arow;
                pa = (gm < M) ? *(const uint4*)(A + (size_t)gm*lda + kn + achk*8) : make_uint4(0,0,0,0);
                pb = *(const uint4*)(B + (size_t)arow*ldb + kn + achk*8);
            }
            bf16x8 af, bfr[4];
            af = *(const bf16x8*)(&As[(w*16 + lr)*APITCH + lq*8]);
            #pragma unroll
            for (int ns = 0; ns < 4; ++ns)
                bfr[ns] = *(const bf16x8*)(&Bs[(ns*16 + lr)*APITCH + lq*8]);
            #pragma unroll
            for (int ns = 0; ns < 4; ++ns)
                acc[ns] = __builtin_amdgcn_mfma_f32_16x16x32_bf16(af, bfr[ns], acc[ns], 0,0,0);
            __syncthreads();
        }
        #pragma unroll
        for (int ns = 0; ns < 4; ++ns) {
            int bc = ns*16 + lr;
            float bv = biasl[bc];
            #pragma unroll
            for (int rg = 0; rg < 4; ++rg) {
                int lrow = w*16 + lq*4 + rg;
                Cs[lrow*MCP + bc] = f2b(acc[ns][rg] + bv);
            }
        }
        __syncthreads();
        #pragma unroll
        for (int it = 0; it < 2; ++it) {
            int i = t + it*256;
            int row = i >> 3, c8 = i & 7;
            int gm = m0 + row;
            if (gm < M)
                *(uint4*)(Cg + (size_t)gm*ldc + n0 + c8*8) = *(const uint4*)(Cs + row*MCP + c8*8);
        }
        return;
    }
    if (blockIdx.x < 257) {
        // ================= wcomb/wfc2/bcomb branch =================
        int b = blockIdx.x - 188;        // 0..68
        if (b < 64) {
            int lp  = 1 + (b >> 5);      // layer index 1,2
            int wb2 = b & 31;            // 32 blocks/layer
            const float* W2f = W2 + (size_t)(lp-1)*262144;
            const float* wm[4];
            #pragma unroll
            for (int i = 0; i < 4; ++i) {
                int row = wb2*4 + i;
                wm[i] = (row < 64) ? (Wsrc + (size_t)lp*16384 + row*256)
                                   : (Wdst + (size_t)lp*16384 + (row-64)*256);
            }
            float acc[4][4] = {};
            int c0 = t*4;
            #pragma unroll 8
            for (int c = 0; c < 256; ++c) {
                float4 w2v = *(const float4*)(W2f + (size_t)c*1024 + c0);
                #pragma unroll
                for (int i = 0; i < 4; ++i) {
                    float wv2 = wm[i][c];
                    acc[i][0] = fmaf(wv2, w2v.x, acc[i][0]);
                    acc[i][1] = fmaf(wv2, w2v.y, acc[i][1]);
                    acc[i][2] = fmaf(wv2, w2v.z, acc[i][2]);
                    acc[i][3] = fmaf(wv2, w2v.w, acc[i][3]);
                }
            }
            int fc = t >> 4, j = (t >> 3) & 1, lq2 = (t >> 1) & 3, cpos = (t & 1) * 4;
            #pragma unroll
            for (int i = 0; i < 4; ++i) {
                int row = wb2*4 + i;
                int wv2 = row >> 5, ns = (row >> 4) & 1, lr2 = row & 15;
                *(ushort4*)(wcomb + (size_t)(lp-1)*131072
                            + (size_t)fc*8192 + wv2*2048 + ns*1024 + j*512 + (lq2*16+lr2)*8 + cpos) =
                    make_ushort4(f2b(acc[i][0]), f2b(acc[i][1]), f2b(acc[i][2]), f2b(acc[i][3]));
            }
        } else if (b < 68) {
            int c = (b - 64)*256 + t;
            const float* W2f = W2 + 2*262144;
            float a0 = 0.f, a1 = 0.f, a2 = 0.f, a3 = 0.f;
            #pragma unroll 4
            for (int k = 0; k < 256; k += 4) {
                a0 = fmaf(Wfc[k+0], W2f[(size_t)(k+0)*1024 + c], a0);
                a1 = fmaf(Wfc[k+1], W2f[(size_t)(k+1)*1024 + c], a1);
                a2 = fmaf(Wfc[k+2], W2f[(size_t)(k+2)*1024 + c], a2);
                a3 = fmaf(Wfc[k+3], W2f[(size_t)(k+3)*1024 + c], a3);
            }
            wfc2[c] = (a0 + a1) + (a2 + a3);
        } else {
            int lp = 1 + (t >> 7);
            int row = t & 127;
            const float* b2l = b2 + (lp-1)*256;
            const float* wmrow = (row < 64) ? (Wsrc + (size_t)lp*16384 + row*256)
                                            : (Wdst + (size_t)lp*16384 + (row-64)*256);
            float acc = 0.f;
            #pragma unroll 8
            for (int c = 0; c < 256; ++c) acc += wmrow[c] * b2l[c];
            acc += (row < 64) ? bias1[lp*64 + row] : bias2[lp*64 + (row-64)];
            bcomb[(lp-1)*128 + row] = acc;
            if (t == 0) {
                float bo = 0.f;
                const float* b23 = b2 + 2*256;
                #pragma unroll 8
                for (int c = 0; c < 256; ++c) bo += Wfc[c] * b23[c];
                out[0] = bo + bfc[0];
            }
        }
        return;
    }
    // ================= eproj v4 (LDS-free, barrier-free, 128 rows/block) =================
    {
        const int m0 = (blockIdx.x - 257) * 128;
        const float gamma = 31.875f;
        const float step  = 8.0f / 255.0f;
        // A fragments in registers: af[s][ks] = row (m0 + s*64 + 16w + lr), k = ks*32+lq*8..+7
        bf16x8 af[2][8];
        #pragma unroll
        for (int s = 0; s < 2; ++s) {
            float dv = dvec[m0 + s*64 + w*16 + lr];
            #pragma unroll
            for (int ks = 0; ks < 8; ++ks) {
                unsigned short h[8];
                int kb = ks*32 + lq*8;
                #pragma unroll
                for (int j = 0; j < 8; ++j) {
                    float tt2 = dv - (float)(kb+j)*step;
                    h[j] = f2b(__expf(-gamma*tt2*tt2));
                }
                af[s][ks] = *(bf16x8*)h;
            }
        }
        const unsigned short* Bl = Bwp + lane*8;
        for (int ct = 0; ct < 12; ++ct) {
            const unsigned short* Bb = Bl + (ct/3)*12288 + (ct%3)*4096;
            uint4 pb[8];
            #pragma unroll
            for (int ks = 0; ks < 8; ++ks)
                pb[ks] = *(const uint4*)(Bb + ks*512);
            floatx4 acc0 = {}, acc1 = {};
            #pragma unroll
            for (int ks = 0; ks < 8; ++ks) {
                acc0 = __builtin_amdgcn_mfma_f32_16x16x32_bf16(
                    af[0][ks], *(const bf16x8*)&pb[ks], acc0, 0, 0, 0);
                acc1 = __builtin_amdgcn_mfma_f32_16x16x32_bf16(
                    af[1][ks], *(const bf16x8*)&pb[ks], acc1, 0, 0, 0);
            }
            int bc = (ct/3)*48 + (ct%3)*16 + lr;
            float bv = bias[bc];
            #pragma unroll
            for (int rg = 0; rg < 4; ++rg) {
                int row = m0 + w*16 + lq*4 + rg;
                C[(size_t)row*192 + bc] = f2b(acc0[rg] + bv);
                C[(size_t)(row + 64)*192 + bc] = f2b(acc1[rg] + bv);
            }
        }
    }
}

// ---------------- fused FF + wcomb with PACKED weight fragments ----------------
#define HP 72
#define CP2 136
__global__ __launch_bounds__(256) void ffw_kernel(
    const unsigned short* __restrict__ XN,   // [N,64] bf16
    const unsigned short* __restrict__ W1p,  // PACKED W1 frags (this layer)
    const float* __restrict__ b1l,           // [1024]
    const unsigned short* __restrict__ WCp,  // PACKED wcomb frags (this layer)
    const float* __restrict__ bcl,           // [128]
    unsigned short* __restrict__ XO,         // [N,128] bf16
    int M) {
    __shared__ __align__(16) unsigned short s_h[16*HP];    // h chunk [16][72]
    __shared__ __align__(16) unsigned short s_c[16*CP2];   // epilogue [16][136]
    const int t = threadIdx.x;
    const int wv = t >> 6, lane = t & 63, lr = lane & 15, lq = lane >> 4;
    const int m0 = blockIdx.x * 16;

    int ga = m0 + lr;
    bool aok = ga < M;
    uint4 a0 = aok ? *(const uint4*)(XN + (size_t)ga*64 + lq*8) : make_uint4(0,0,0,0);
    uint4 a1 = aok ? *(const uint4*)(XN + (size_t)ga*64 + 32 + lq*8) : make_uint4(0,0,0,0);

    floatx4 acc2[2] = {};

    const unsigned short* W1b = W1p + (size_t)wv*1024 + lane*8;   // + f*4096 + j*512
    const unsigned short* WCb = WCp + (size_t)wv*2048 + lane*8;   // + f*8192 + ns*1024 + j*512

    uint4 pb1[2], pb2[4];
    pb1[0] = *(const uint4*)(W1b);
    pb1[1] = *(const uint4*)(W1b + 512);
    pb2[0] = *(const uint4*)(WCb);
    pb2[1] = *(const uint4*)(WCb + 512);
    pb2[2] = *(const uint4*)(WCb + 1024);
    pb2[3] = *(const uint4*)(WCb + 1536);

    for (int f = 0; f < 16; ++f) {
        uint4 cb1_0 = pb1[0], cb1_1 = pb1[1];
        uint4 cb2_0 = pb2[0], cb2_1 = pb2[1], cb2_2 = pb2[2], cb2_3 = pb2[3];
        float bv1 = b1l[f*64 + wv*16 + lr];
        if (f < 15) {
            const unsigned short* n1 = W1b + (f+1)*4096;
            const unsigned short* n2 = WCb + (f+1)*8192;
            pb1[0] = *(const uint4*)(n1);
            pb1[1] = *(const uint4*)(n1 + 512);
            pb2[0] = *(const uint4*)(n2);
            pb2[1] = *(const uint4*)(n2 + 512);
            pb2[2] = *(const uint4*)(n2 + 1024);
            pb2[3] = *(const uint4*)(n2 + 1536);
        }
        floatx4 hacc = {};
        hacc = __builtin_amdgcn_mfma_f32_16x16x32_bf16(
            *(const bf16x8*)&a0, *(const bf16x8*)&cb1_0, hacc, 0,0,0);
        hacc = __builtin_amdgcn_mfma_f32_16x16x32_bf16(
            *(const bf16x8*)&a1, *(const bf16x8*)&cb1_1, hacc, 0,0,0);
        {
            int col = wv*16 + lr;
            #pragma unroll
            for (int rg = 0; rg < 4; ++rg) {
                int row = lq*4 + rg;
                s_h[row*HP + col] = f2b(silu_f(hacc[rg] + bv1));
            }
        }
        __syncthreads();
        bf16x8 ha0 = *(const bf16x8*)(&s_h[lr*HP + lq*8]);
        bf16x8 ha1 = *(const bf16x8*)(&s_h[lr*HP + 32 + lq*8]);
        acc2[0] = __builtin_amdgcn_mfma_f32_16x16x32_bf16(ha0, *(const bf16x8*)&cb2_0, acc2[0], 0,0,0);
        acc2[0] = __builtin_amdgcn_mfma_f32_16x16x32_bf16(ha1, *(const bf16x8*)&cb2_1, acc2[0], 0,0,0);
        acc2[1] = __builtin_amdgcn_mfma_f32_16x16x32_bf16(ha0, *(const bf16x8*)&cb2_2, acc2[1], 0,0,0);
        acc2[1] = __builtin_amdgcn_mfma_f32_16x16x32_bf16(ha1, *(const bf16x8*)&cb2_3, acc2[1], 0,0,0);
        __syncthreads();
    }

    #pragma unroll
    for (int ns = 0; ns < 2; ++ns) {
        int col = wv*32 + ns*16 + lr;
        float bv = bcl[col];
        #pragma unroll
        for (int rg = 0; rg < 4; ++rg) {
            int row = lq*4 + rg;
            s_c[row*CP2 + col] = f2b(acc2[ns][rg] + bv);
        }
    }
    __syncthreads();
    {
        int row = t >> 4, c8 = t & 15;
        int gm = m0 + row;
        if (gm < M)
            *(uint4*)(XO + (size_t)gm*128 + c8*8) = *(const uint4*)(s_c + row*CP2 + c8*8);
    }
}

// ---------------- layer-2 FF + fused final reduction (packed W1, barrier-free loop) ----------------
__global__ __launch_bounds__(256) void ffa_kernel(
    const unsigned short* __restrict__ XN,   // [N,64] bf16
    const unsigned short* __restrict__ W1p,  // PACKED W1 frags (layer 2)
    const float* __restrict__ b1l,           // [1024]
    const float* __restrict__ wfc2,          // [1024]
    float* __restrict__ out, int M) {
    __shared__ float red[256];
    const int t = threadIdx.x;
    const int wv = t >> 6, lane = t & 63, lr = lane & 15, lq = lane >> 4;
    const int m0 = blockIdx.x * 16;

    int ga = m0 + lr;
    bool aok = ga < M;
    uint4 a0 = aok ? *(const uint4*)(XN + (size_t)ga*64 + lq*8) : make_uint4(0,0,0,0);
    uint4 a1 = aok ? *(const uint4*)(XN + (size_t)ga*64 + 32 + lq*8) : make_uint4(0,0,0,0);

    const unsigned short* W1b = W1p + (size_t)wv*1024 + lane*8;
    uint4 pb0 = *(const uint4*)(W1b);
    uint4 pb1 = *(const uint4*)(W1b + 512);

    float partial = 0.f;
    for (int f = 0; f < 16; ++f) {
        uint4 c0 = pb0, c1 = pb1;
        if (f < 15) {
            pb0 = *(const uint4*)(W1b + (f+1)*4096);
            pb1 = *(const uint4*)(W1b + (f+1)*4096 + 512);
        }
        floatx4 hacc = {};
        hacc = __builtin_amdgcn_mfma_f32_16x16x32_bf16(
            *(const bf16x8*)&a0, *(const bf16x8*)&c0, hacc, 0,0,0);
        hacc = __builtin_amdgcn_mfma_f32_16x16x32_bf16(
            *(const bf16x8*)&a1, *(const bf16x8*)&c1, hacc, 0,0,0);
        float bv1 = b1l[f*64 + wv*16 + lr];
        float wvv = wfc2[f*64 + wv*16 + lr];
        #pragma unroll
        for (int rg = 0; rg < 4; ++rg) {
            int gm = m0 + lq*4 + rg;
            if (gm < M) partial += silu_f(hacc[rg] + bv1) * wvv;
        }
    }
    red[t] = partial;
    __syncthreads();
    for (int off = 128; off > 0; off >>= 1) {
        if (t < off) red[t] += red[t+off];
        __syncthreads();
    }
    if (t == 0) atomicAdd(out, red[0] * (1.0f/(float)N_NODES));
}

// ---------------- angle attention v3: split-k logits + full-width shuffle softmax ----------------
__global__ __launch_bounds__(256) void angle_kernel(
    const unsigned short* __restrict__ xjxi,
    const unsigned short* __restrict__ eproj,
    const float* __restrict__ rhat,
    const int*   __restrict__ src,
    const float* __restrict__ attn,
    unsigned short* __restrict__ xn) {
    __shared__ __align__(16) float s_xij[16][68];
    __shared__ float s_rhat[16][4];
    __shared__ float s_logit[16][17];
    __shared__ float s_a[16][17];
    __shared__ float s_w[16];
    const int tt = threadIdx.x;
    const int node = blockIdx.x;

    if (tt < 16) {
        float4 rv = *(const float4*)(rhat + (size_t)(node*DEG_ + tt)*4);
        s_rhat[tt][0] = rv.x; s_rhat[tt][1] = rv.y; s_rhat[tt][2] = rv.z; s_rhat[tt][3] = 0.f;
        s_logit[tt][tt] = -1e30f;      // diag -> exp() == 0
    }
    {
        int p = tt >> 4, c4 = tt & 15;    // 256 threads: 16 edges x 16 chunks of 4 elems
        int e = node*DEG_ + p;
        int se = src[e];
        ushort4 aj = *(const ushort4*)(xjxi + (size_t)se*128 + c4*4);
        ushort4 ai = *(const ushort4*)(xjxi + (size_t)node*128 + 64 + c4*4);
        ushort4 ae = *(const ushort4*)(eproj + (size_t)e*192 + c4*4);
        s_xij[p][c4*4+0] = b2f(aj.x) + b2f(ai.x) + b2f(ae.x);
        s_xij[p][c4*4+1] = b2f(aj.y) + b2f(ai.y) + b2f(ae.y);
        s_xij[p][c4*4+2] = b2f(aj.z) + b2f(ai.z) + b2f(ae.z);
        s_xij[p][c4*4+3] = b2f(aj.w) + b2f(ai.w) + b2f(ae.w);
    }
    __syncthreads();
    int pp = 0, qq = 0;
    float lg = 0.f;
    if (tt < 240) {
        int pair = tt >> 1, half = tt & 1;
        pp = (int)((1.0f + sqrtf(8.0f*(float)pair + 1.0f)) * 0.5f);
        qq = pair - ((pp*(pp-1)) >> 1);
        float c = s_rhat[pp][0]*s_rhat[qq][0] + s_rhat[pp][1]*s_rhat[qq][1]
                + s_rhat[pp][2]*s_rhat[qq][2];
        c = fminf(fmaxf(c, -0.999999f), 0.999999f);
        float c2 = 2.0f * c;
        float tk0, tk1;
        if (half) {
            float T2  = fmaf(c2, c, -1.0f);
            float T3  = fmaf(2.0f*T2,  c,   -c);
            float T4  = fmaf(2.0f*T2,  T2,  -1.0f);
            float T7  = fmaf(2.0f*T4,  T3,  -c);
            float T8  = fmaf(2.0f*T4,  T4,  -1.0f);
            float T15 = fmaf(2.0f*T8,  T7,  -c);
            float T16 = fmaf(2.0f*T8,  T8,  -1.0f);
            float T31 = fmaf(2.0f*T16, T15, -c);
            float T32 = fmaf(2.0f*T16, T16, -1.0f);
            float T33 = fmaf(2.0f*T32, c,   -T31);
            tk0 = T32; tk1 = T33;
        } else {
            tk0 = 1.0f; tk1 = c;
        }
        const float* xp = &s_xij[pp][0] + half*32;
        const float* xq = &s_xij[qq][0] + half*32;
        const float* at = attn + half*32;
        float acc = 0.f;
        #pragma unroll
        for (int k0 = 0; k0 < 32; k0 += 4) {
            float4 xp4 = *(const float4*)(xp + k0);
            float4 xq4 = *(const float4*)(xq + k0);
            float a0 = at[k0+0], a1 = at[k0+1], a2 = at[k0+2], a3 = at[k0+3];
            float v0 = tk0 + xp4.x + xq4.x;
            acc = fmaf(a0, silu_f(v0), acc);
            { float tn2 = c2*tk1 - tk0; tk0 = tk1; tk1 = tn2; }
            float v1 = tk0 + xp4.y + xq4.y;
            acc = fmaf(a1, silu_f(v1), acc);
            { float tn2 = c2*tk1 - tk0; tk0 = tk1; tk1 = tn2; }
            float v2 = tk0 + xp4.z + xq4.z;
            acc = fmaf(a2, silu_f(v2), acc);
            { float tn2 = c2*tk1 - tk0; tk0 = tk1; tk1 = tn2; }
            float v3 = tk0 + xp4.w + xq4.w;
            acc = fmaf(a3, silu_f(v3), acc);
            { float tn2 = c2*tk1 - tk0; tk0 = tk1; tk1 = tn2; }
        }
        lg = acc;
    }
    lg += __shfl_xor(lg, 1);
    if (tt < 240 && (tt & 1) == 0) {
        s_logit[pp][qq] = lg;
        s_logit[qq][pp] = lg;
    }
    __syncthreads();
    // column softmax: thread (q = tt>>4, p = tt&15); shfl groups of 16 share q
    {
        int q = tt >> 4, p = tt & 15;
        float l = s_logit[p][q];
        float m = l;
        m = fmaxf(m, __shfl_xor(m, 1));
        m = fmaxf(m, __shfl_xor(m, 2));
        m = fmaxf(m, __shfl_xor(m, 4));
        m = fmaxf(m, __shfl_xor(m, 8));
        float e = __expf(l - m);
        float z = e;
        z += __shfl_xor(z, 1);
        z += __shfl_xor(z, 2);
        z += __shfl_xor(z, 4);
        z += __shfl_xor(z, 8);
        s_a[p][q] = e * __builtin_amdgcn_rcpf(z);   // attention weight, zi folded in
    }
    __syncthreads();
    // row-sum: thread (p = tt>>4, q = tt&15); sw[p] = sum_q a[p][q]
    {
        int p = tt >> 4, q = tt & 15;
        float a = s_a[p][q];
        a += __shfl_xor(a, 1);
        a += __shfl_xor(a, 2);
        a += __shfl_xor(a, 4);
        a += __shfl_xor(a, 8);
        if (q == 0) s_w[p] = a;
    }
    __syncthreads();
    if (tt < 64) {
        float acc = 0.f;
        #pragma unroll
        for (int p = 0; p < 16; ++p) acc += s_w[p] * s_xij[p][tt];
        xn[(size_t)node*64 + tt] = f2b(acc);
    }
}

extern "C" void kernel_launch(void* const* d_in, const int* in_sizes, int n_in,
                              void* d_out, int out_size, void* d_ws, size_t ws_size,
                              hipStream_t stream) {
    (void)in_sizes; (void)n_in; (void)out_size; (void)ws_size;
    const float* r    = (const float*)d_in[0];
    const int*   an   = (const int*)  d_in[1];
    const int*   src  = (const int*)  d_in[2];
    const float* emb  = (const float*)d_in[6];
    const float* Wsrc = (const float*)d_in[7];
    const float* bsrc = (const float*)d_in[8];
    const float* Wdst = (const float*)d_in[9];
    const float* bdst = (const float*)d_in[10];
    const float* Wedge= (const float*)d_in[11];
    const float* bedge= (const float*)d_in[12];
    const float* attn = (const float*)d_in[13];
    const float* W1   = (const float*)d_in[14];
    const float* b1   = (const float*)d_in[15];
    const float* W2   = (const float*)d_in[16];
    const float* b2   = (const float*)d_in[17];
    const float* Wfc  = (const float*)d_in[18];
    const float* bfc  = (const float*)d_in[19];

    char* ws = (char*)d_ws;
    float* d_d              = (float*)(ws);                    // 384000 B
    float* d_rhat           = (float*)(ws + 384000);           // 1536000 B
    unsigned short* wbf     = (unsigned short*)(ws + 1920000); // 196608 B (wsrc/wdst bf16)
    unsigned short* d_x     = (unsigned short*)(ws + 4180992); // 3072000 B
    unsigned short* d_xjxi  = (unsigned short*)(ws + 7252992); // 1536000 B
    unsigned short* d_eproj = (unsigned short*)(ws + 8788992); // 36864000 B
    unsigned short* d_xn    = (unsigned short*)(ws + 45652992);// 768000 B
    unsigned short* d_wcomb = (unsigned short*)(ws + 46420992);// 524288 B (packed)
    float* d_bcomb          = (float*)(ws + 46945280);         // 1024 B
    float* d_wfc2           = (float*)(ws + 46946304);         // 4096 B
    unsigned short* d_wedgep= (unsigned short*)(ws + 46950400);// 98304 B (packed)
    unsigned short* d_w1p   = (unsigned short*)(ws + 47048704);// 393216 B (packed, 3 layers)
    float* out = (float*)d_out;

    unsigned short* wsrc_bf  = wbf + WSRC_OFF;
    unsigned short* wdst_bf  = wbf + WDST_OFF;

    // fast prep (only what eplg needs) -> eplg starts ASAP
    prep_kernel<<<CVT4_BLOCKS + EMB4_BLOCKS + GEOM_BLOCKS + WPACKE_BLOCKS + WPACK1_BLOCKS,
                  256, 0, stream>>>(
        Wsrc, Wdst, Wedge, W1, wbf, an, emb, d_x, r, d_d, d_rhat, d_wedgep, d_w1p);

    // merged GEMM [0,188) + wcomb [188,257) + eproj [257,1007)
    eplg_kernel<<<188 + 69 + 750, 256, 0, stream>>>(
        d_wedgep, bedge, d_d, d_eproj,
        d_x, wsrc_bf, wdst_bf, bsrc, bdst, d_xjxi,
        Wsrc, Wdst, W2, b2, Wfc, bfc,
        d_wcomb, d_bcomb, d_wfc2, out);

    // ---- layer 0 ----
    angle_kernel<<<N_NODES, 256, 0, stream>>>(
        d_xjxi, d_eproj, d_rhat, src, attn, d_xn);
    ffw_kernel<<<375, 256, 0, stream>>>(
        d_xn, d_w1p, b1, d_wcomb, d_bcomb, d_xjxi, N_NODES);

    // ---- layer 1 ----
    angle_kernel<<<N_NODES, 256, 0, stream>>>(
        d_xjxi, d_eproj + 64, d_rhat, src, attn + 64, d_xn);
    ffw_kernel<<<375, 256, 0, stream>>>(
        d_xn, d_w1p + 65536, b1 + 1024, d_wcomb + 131072, d_bcomb + 128, d_xjxi, N_NODES);

    // ---- layer 2 (FF + final reduction, packed W1, barrier-free loop) ----
    angle_kernel<<<N_NODES, 256, 0, stream>>>(
        d_xjxi, d_eproj + 128, d_rhat, src, attn + 128, d_xn);
    ffa_kernel<<<375, 256, 0, stream>>>(
        d_xn, d_w1p + 131072, b1 + 2048, d_wfc2, out, N_NODES);
}